// Round 7
// baseline (76.375 us; speedup 1.0000x reference)
//
#include <hip/hip_runtime.h>
#include <math.h>

#define NQ 10
#define NL 4
#define NGATES (NL * NQ)
#define NTHREADS 256
#define WPB 4   // waves per block

typedef float f32x2 __attribute__((ext_vector_type(2)));

#if __has_builtin(__builtin_amdgcn_permlane32_swap)
#define HAVE_PLSWAP 1
#else
#define HAVE_PLSWAP 0
#endif

// ---------------------------------------------------------------------------
// Physical bit layout (10-bit state index split lane(6)/reg(4)):
//   qubit0 -> lane 16   qubit1 -> lane 8   qubit2 -> lane 4   (ds_swizzle bits)
//   qubit7 -> lane 32 (permlane)  qubit8 -> lane 2 (DPP)  qubit9 -> lane 1 (DPP)
//   qubit3 -> reg 8   qubit4 -> reg 4   qubit5 -> reg 2   qubit6 -> reg 1
// CNOT chain K = prefix-parity matrix; CNOTs absorbed into basis relabeling.
// Gate on qubit q in layer l: xor-mask m = K^{-l} e_q, select s = row_q(K^l).
// All 40 (mask, select) pairs constexpr (validated rounds 2-6).
// ---------------------------------------------------------------------------

// 32-bit xor-exchange by compile-time lane mask XM
template<int XM>
__device__ __forceinline__ float exch1(float v, bool selP) {
    if constexpr (XM == 0) return v;
    int x = __float_as_int(v);
    constexpr int low = XM & 31;
    if constexpr (low == 1)      x = __builtin_amdgcn_mov_dpp(x, 0xB1, 0xF, 0xF, true);
    else if constexpr (low == 2) x = __builtin_amdgcn_mov_dpp(x, 0x4E, 0xF, 0xF, true);
    else if constexpr (low == 3) x = __builtin_amdgcn_mov_dpp(x, 0x1B, 0xF, 0xF, true);
    else if constexpr (low != 0) x = __builtin_amdgcn_ds_swizzle(x, (low << 10) | 0x1F);
    if constexpr ((XM & 32) != 0) {
#if HAVE_PLSWAP
        auto r = __builtin_amdgcn_permlane32_swap((unsigned)x, (unsigned)x, false, false);
        x = selP ? (int)r[0] : (int)r[1];
#else
        x = __float_as_int(__shfl_xor(__int_as_float(x), 32, 64));
#endif
    }
    return __int_as_float(x);
}

template<int XM>
__device__ __forceinline__ f32x2 exch2(f32x2 v, bool selP) {
    f32x2 r;
    r.x = exch1<XM>(v.x, selP);
    r.y = exch1<XM>(v.y, selP);
    return r;
}

// generalized 1q gate: pair (p, p^m); select h = parity(p & s).
// Complex update st[r] = A_r*st[r] + B_r*pst[r] in VOP3P packed f32, emitted
// as 4 asm blocks of 4 registers with STAGE-INTERLEAVED instructions so each
// dependent op is 4 insts (>= 8 cycles) after its producer: latency-hidden
// by construction (2 waves/SIMD can't hide it for us).
template<int XM, int XR, int SL, int SR>
__device__ __forceinline__ void gate(f32x2 (&st)[16], const f32x2* g4,
                                     int lane, bool selP) {
    f32x2 u00 = g4[0], u01 = g4[1], u10 = g4[2], u11 = g4[3];
    bool hl = (SL != 0) && ((__popc(lane & SL) & 1) != 0);
    f32x2 A0, B0, A1, B1;
    A0.x = hl ? u11.x : u00.x;  A0.y = hl ? u11.y : u00.y;
    B0.x = hl ? u10.x : u01.x;  B0.y = hl ? u10.y : u01.y;
    A1.x = hl ? u00.x : u11.x;  A1.y = hl ? u00.y : u11.y;
    B1.x = hl ? u01.x : u10.x;  B1.y = hl ? u01.y : u10.y;
    f32x2 pst[16];
    #pragma unroll
    for (int r = 0; r < 16; ++r) pst[r] = exch2<XM>(st[r ^ XR], selP);

#define AR(r) ((__builtin_popcount((r) & SR) & 1) ? A1 : A0)   /* folds: r,SR const */
#define BR(r) ((__builtin_popcount((r) & SR) & 1) ? B1 : B0)
#define QBLK(r0, r1, r2, r3)                                                          \
    {                                                                                 \
        f32x2 t0, t1, t2, t3;                                                         \
        asm("v_pk_mul_f32 %0, %4, %12 op_sel:[0,0] op_sel_hi:[0,1]\n\t"               \
            "v_pk_mul_f32 %1, %5, %13 op_sel:[0,0] op_sel_hi:[0,1]\n\t"               \
            "v_pk_mul_f32 %2, %6, %14 op_sel:[0,0] op_sel_hi:[0,1]\n\t"               \
            "v_pk_mul_f32 %3, %7, %15 op_sel:[0,0] op_sel_hi:[0,1]\n\t"               \
            "v_pk_fma_f32 %0, %4, %12, %0 op_sel:[1,1,0] op_sel_hi:[1,0,1] neg_lo:[0,1,0]\n\t" \
            "v_pk_fma_f32 %1, %5, %13, %1 op_sel:[1,1,0] op_sel_hi:[1,0,1] neg_lo:[0,1,0]\n\t" \
            "v_pk_fma_f32 %2, %6, %14, %2 op_sel:[1,1,0] op_sel_hi:[1,0,1] neg_lo:[0,1,0]\n\t" \
            "v_pk_fma_f32 %3, %7, %15, %3 op_sel:[1,1,0] op_sel_hi:[1,0,1] neg_lo:[0,1,0]\n\t" \
            "v_pk_fma_f32 %0, %8, %16, %0 op_sel:[0,0,0] op_sel_hi:[0,1,1]\n\t"       \
            "v_pk_fma_f32 %1, %9, %17, %1 op_sel:[0,0,0] op_sel_hi:[0,1,1]\n\t"       \
            "v_pk_fma_f32 %2, %10, %18, %2 op_sel:[0,0,0] op_sel_hi:[0,1,1]\n\t"      \
            "v_pk_fma_f32 %3, %11, %19, %3 op_sel:[0,0,0] op_sel_hi:[0,1,1]\n\t"      \
            "v_pk_fma_f32 %0, %8, %16, %0 op_sel:[1,1,0] op_sel_hi:[1,0,1] neg_lo:[0,1,0]\n\t" \
            "v_pk_fma_f32 %1, %9, %17, %1 op_sel:[1,1,0] op_sel_hi:[1,0,1] neg_lo:[0,1,0]\n\t" \
            "v_pk_fma_f32 %2, %10, %18, %2 op_sel:[1,1,0] op_sel_hi:[1,0,1] neg_lo:[0,1,0]\n\t" \
            "v_pk_fma_f32 %3, %11, %19, %3 op_sel:[1,1,0] op_sel_hi:[1,0,1] neg_lo:[0,1,0]"    \
            : "=&v"(t0), "=&v"(t1), "=&v"(t2), "=&v"(t3)                              \
            : "v"(AR(r0)), "v"(AR(r1)), "v"(AR(r2)), "v"(AR(r3)),                     \
              "v"(BR(r0)), "v"(BR(r1)), "v"(BR(r2)), "v"(BR(r3)),                     \
              "v"(st[r0]), "v"(st[r1]), "v"(st[r2]), "v"(st[r3]),                     \
              "v"(pst[r0]), "v"(pst[r1]), "v"(pst[r2]), "v"(pst[r3]));                \
        st[r0] = t0; st[r1] = t1; st[r2] = t2; st[r3] = t3;                           \
    }
    QBLK(0, 1, 2, 3)
    QBLK(4, 5, 6, 7)
    QBLK(8, 9, 10, 11)
    QBLK(12, 13, 14, 15)
#undef QBLK
#undef AR
#undef BR
}

// 6-stage signed butterfly: lane L ends with sum_j (-1)^{popcount(L&j)} v_j
__device__ __forceinline__ float wht6(float v, int lane, bool selP) {
    float t;
    t = exch1<1>(v, selP);   v = (lane & 1)  ? (t - v) : (v + t);
    t = exch1<2>(v, selP);   v = (lane & 2)  ? (t - v) : (v + t);
    t = exch1<4>(v, selP);   v = (lane & 4)  ? (t - v) : (v + t);
    t = exch1<8>(v, selP);   v = (lane & 8)  ? (t - v) : (v + t);
    t = exch1<16>(v, selP);  v = (lane & 16) ? (t - v) : (v + t);
    t = exch1<32>(v, selP);  v = (lane & 32) ? (t - v) : (v + t);
    return v;
}

__global__ __launch_bounds__(NTHREADS, 2) void qlayer_kernel(
    const float* __restrict__ x,
    const float* __restrict__ qp,
    float* __restrict__ out,
    int B)
{
    __shared__ f32x2 su[NGATES][4];   // {u00, u01, u10, u11} as (re,im) pairs

    const int t = threadIdx.x;
    // --- build gate matrices U = Rz @ Ry @ Rx, threads 0..39 ---
    if (t < NGATES) {
        float w0 = qp[t * 3 + 0], w1 = qp[t * 3 + 1], w2 = qp[t * 3 + 2];
        float cx = __cosf(0.5f * w0), sx = __sinf(0.5f * w0);
        float cy = __cosf(0.5f * w1), sy = __sinf(0.5f * w1);
        float er = __cosf(0.5f * w2), ei = -__sinf(0.5f * w2);   // ez = exp(-i w2/2)
        float m00r =  cy * cx, m00i =  sy * sx;
        float m01r = -sy * cx, m01i = -cy * sx;
        float m10r =  sy * cx, m10i = -cy * sx;
        float m11r =  cy * cx, m11i = -sy * sx;
        f32x2 v;
        v.x = er * m00r - ei * m00i;  v.y = er * m00i + ei * m00r;  su[t][0] = v;
        v.x = er * m01r - ei * m01i;  v.y = er * m01i + ei * m01r;  su[t][1] = v;
        v.x = er * m10r + ei * m10i;  v.y = er * m10i - ei * m10r;  su[t][2] = v;
        v.x = er * m11r + ei * m11i;  v.y = er * m11i - ei * m11r;  su[t][3] = v;
    }
    __syncthreads();

    const int lane = t & 63;
    const int b = blockIdx.x * WPB + (t >> 6);
    if (b >= B) return;

    // runtime probe: which permlane32_swap output holds the lane^32 partner
    bool selP = false;
#if HAVE_PLSWAP
    {
        auto pr = __builtin_amdgcn_permlane32_swap((unsigned)lane, (unsigned)lane, false, false);
        selP = ((int)pr[0] == (lane ^ 32));
    }
#endif

    float c[NQ], s[NQ];
    #pragma unroll
    for (int q = 0; q < NQ; ++q) {
        float h = 0.5f * x[b * NQ + q];
        c[q] = __cosf(h);  s[q] = __sinf(h);
    }

    // initial product state per physical layout
    float lf = ((lane & 16) ? s[0] : c[0]) * ((lane & 8) ? s[1] : c[1]) *
               ((lane &  4) ? s[2] : c[2]) * ((lane & 32) ? s[7] : c[7]) *
               ((lane &  2) ? s[8] : c[8]) * ((lane &  1) ? s[9] : c[9]);
    f32x2 st[16];
    #pragma unroll
    for (int r = 0; r < 16; ++r) {
        st[r].x = lf * ((r & 8) ? s[3] : c[3]) * ((r & 4) ? s[4] : c[4]) *
                       ((r & 2) ? s[5] : c[5]) * ((r & 1) ? s[6] : c[6]);
        st[r].y = 0.0f;
    }

#define GATE(L, Q, XM, XR, SLm, SRm) \
    gate<XM, XR, SLm, SRm>(st, &su[(L)*NQ+(Q)][0], lane, selP);

    // layer 0 (A = I)
    GATE(0,0, 16,0, 16,0)  GATE(0,1, 8,0, 8,0)   GATE(0,2, 4,0, 4,0)
    GATE(0,3, 0,8, 0,8)    GATE(0,4, 0,4, 0,4)   GATE(0,5, 0,2, 0,2)
    GATE(0,6, 0,1, 0,1)    GATE(0,7, 32,0, 32,0) GATE(0,8, 2,0, 2,0)
    GATE(0,9, 1,0, 1,0)
    // layer 1 (A = K)
    GATE(1,0, 24,0, 16,0)  GATE(1,1, 12,0, 24,0) GATE(1,2, 4,8, 28,0)
    GATE(1,3, 0,12, 28,8)  GATE(1,4, 0,6, 28,12) GATE(1,5, 0,3, 28,14)
    GATE(1,6, 32,1, 28,15) GATE(1,7, 34,0, 60,15) GATE(1,8, 3,0, 62,15)
    GATE(1,9, 1,0, 63,15)
    // layer 2 (A = K^2)
    GATE(2,0, 20,0, 16,0)  GATE(2,1, 8,8, 8,0)   GATE(2,2, 4,4, 20,0)
    GATE(2,3, 0,10, 8,8)   GATE(2,4, 0,5, 20,4)  GATE(2,5, 32,2, 8,10)
    GATE(2,6, 2,1, 20,5)   GATE(2,7, 33,0, 40,10) GATE(2,8, 2,0, 22,5)
    GATE(2,9, 1,0, 41,10)
    // layer 3 (A = K^3)
    GATE(3,0, 28,8, 16,0)  GATE(3,1, 12,12, 24,0) GATE(3,2, 4,14, 12,0)
    GATE(3,3, 0,15, 4,8)   GATE(3,4, 32,7, 16,12) GATE(3,5, 34,3, 24,6)
    GATE(3,6, 35,1, 12,3)  GATE(3,7, 35,0, 36,9)  GATE(3,8, 3,0, 50,12)
    GATE(3,9, 1,0, 27,6)
#undef GATE

    // epilogue: probabilities, reg-space signed folds, 5 lane-space WHTs
    float p[16];
    #pragma unroll
    for (int r = 0; r < 16; ++r) p[r] = st[r].x * st[r].x + st[r].y * st[r].y;
    float a[8], f8 = 0.0f;
    #pragma unroll
    for (int r = 0; r < 8; ++r) { a[r] = p[r] + p[r + 8]; f8 += p[r] - p[r + 8]; }
    float c4[4], f4 = 0.0f;
    #pragma unroll
    for (int r = 0; r < 4; ++r) { c4[r] = a[r] + a[r + 4]; f4 += a[r] - a[r + 4]; }
    float e2[2], f2 = 0.0f;
    #pragma unroll
    for (int r = 0; r < 2; ++r) { e2[r] = c4[r] + c4[r + 2]; f2 += c4[r] - c4[r + 2]; }
    float P  = e2[0] + e2[1];
    float f1 = e2[0] - e2[1];

    float wP = wht6(P,  lane, selP);
    float w8 = wht6(f8, lane, selP);
    float w4 = wht6(f4, lane, selP);
    float w2 = wht6(f2, lane, selP);
    float w1 = wht6(f1, lane, selP);

    // rows of K^4: {i, i-4, i-8} -> (value, lane index)
    float* o = out + b * NQ;
    if (lane == 16) { o[0] = wP; o[4] = w4; }
    if (lane ==  8) { o[1] = wP; o[5] = w2; }
    if (lane ==  4) { o[2] = wP; o[6] = w1; }
    if (lane ==  0) { o[3] = w8; }
    if (lane == 32) { o[7] = w8; }
    if (lane == 18) { o[8] = w4; }
    if (lane ==  9) { o[9] = w2; }
}

extern "C" void kernel_launch(void* const* d_in, const int* in_sizes, int n_in,
                              void* d_out, int out_size, void* d_ws, size_t ws_size,
                              hipStream_t stream) {
    const float* x  = (const float*)d_in[0];
    const float* qp = (const float*)d_in[1];
    float* out = (float*)d_out;
    const int B = in_sizes[0] / NQ;
    const int blocks = (B + WPB - 1) / WPB;
    qlayer_kernel<<<blocks, NTHREADS, 0, stream>>>(x, qp, out, B);
}